// Round 3
// baseline (1352.957 us; speedup 1.0000x reference)
//
#include <hip/hip_runtime.h>
#include <cmath>

// ---------------------------------------------------------------------------
// NeWCRFBlock: unary MLP + window-attention + MLP, B=8 C=256 H=W=128 WS=8 NH=8
// Round-5 changes:
//   * T2 XOR-swizzle on all GEMM LDS tiles (fixes 8-way ds_read_b128 bank
//     conflict introduced by the stride-32 linear layout): linear gload_lds
//     dest + pre-swizzled GLOBAL source + swizzled frag reads (G21).
//   * Window token order restored (round-0-validated attn; EPI_WINREV again,
//     free under the C^T packed epilogue).
//   * LN affine folded into weights/biases (transpose_f32_bf16 takes scale;
//     bias_fold computes b + beta@W). LN passes emit (x-mu)*rs only.
//   * cvt_f32_bf16 deleted: unary GEMM1 reg-stages f32 A, converts inline.
//   * MLP ln_rows/tch deleted: ln2_stats pass + GEMM1 applies LN in staging.
//   * QKV merged into one N=768 GEMM with 3-way output routing.
// ---------------------------------------------------------------------------

typedef unsigned short u16;
typedef unsigned int u32;
typedef __bf16 bf16x8 __attribute__((ext_vector_type(8)));
typedef float f32x4 __attribute__((ext_vector_type(4)));

#define EPI_NONE 0
#define EPI_GELU 1
#define EPI_WINREV 2
#define EPI_ADD 3

#define MTOK 131072
#define CC 256
#define HWC 16384

__device__ __forceinline__ float b2f(u16 u) {
    union { u32 i; float f; } x; x.i = ((u32)u) << 16; return x.f;
}
__device__ __forceinline__ u16 f2b(float f) {
    union { float f; u32 i; } x; x.f = f;
    u32 r = x.i + 0x7fffu + ((x.i >> 16) & 1u);
    return (u16)(r >> 16);
}
__device__ __forceinline__ u32 cvtpk(float lo, float hi) {
    u32 r;
    asm("v_cvt_pk_bf16_f32 %0, %1, %2" : "=v"(r) : "v"(lo), "v"(hi));
    return r;
}
__device__ __forceinline__ float gelu_f(float v) {
    return 0.5f * v * (1.0f + erff(v * 0.7071067811865475f));
}
// (bf16 pair word) -> LN'd bf16 pair word: y = (x - mu)*rs = fma(x, rs, -mu*rs)
__device__ __forceinline__ u32 ln_word(u32 w, float rs, float nmurs) {
    union { u32 i; float f; } lo, hi;
    lo.i = w << 16; hi.i = w & 0xffff0000u;
    return cvtpk(fmaf(lo.f, rs, nmurs), fmaf(hi.f, rs, nmurs));
}

// ---------------------------------------------------------------------------
// Weight transpose + optional per-row scale + downcast:
//   dst_bf16[n*K+k] = src_f32[k*N+n] * (scale ? scale[k] : 1)
// ---------------------------------------------------------------------------
__global__ __launch_bounds__(256) void transpose_f32_bf16(
    const float* __restrict__ src, const float* __restrict__ scale,
    u16* __restrict__ dst, int K, int N)
{
    __shared__ float t[32][33];
    const int k0 = blockIdx.x * 32, n0 = blockIdx.y * 32;
    const int tx = threadIdx.x & 31, ty = threadIdx.x >> 5;
    for (int i = ty; i < 32; i += 8) {
        float sc = scale ? scale[k0 + i] : 1.0f;
        t[i][tx] = src[(long)(k0 + i) * N + n0 + tx] * sc;
    }
    __syncthreads();
    for (int i = ty; i < 32; i += 8)
        dst[(long)(n0 + i) * K + k0 + tx] = f2b(t[tx][i]);
}

// ---------------------------------------------------------------------------
// Folded bias: out[n] = b[n] + sum_k beta[k] * W[k*N+n]
// ---------------------------------------------------------------------------
__global__ __launch_bounds__(256) void bias_fold(
    const float* __restrict__ W, const float* __restrict__ b,
    const float* __restrict__ beta, float* __restrict__ out, int K, int N)
{
    int n = blockIdx.x * 256 + threadIdx.x;
    if (n >= N) return;
    float s = b[n];
    for (int k = 0; k < K; k++) s += beta[k] * W[(long)k * N + n];
    out[n] = s;
}

// ---------------------------------------------------------------------------
// Bias prepack for attn (f32), MFMA C-fragment layout, sigma-permuted keys.
// ---------------------------------------------------------------------------
__global__ __launch_bounds__(256) void rpb_gather(
    const float* __restrict__ rpb, const int* __restrict__ rel, float* __restrict__ outb)
{
    int e = blockIdx.x * 256 + threadIdx.x;   // 32768 total
    int h = e >> 12, idx = e & 4095;
    int mi = idx >> 10, ni = (idx >> 8) & 3, lane = (idx >> 2) & 63, r = idx & 3;
    int row = mi * 16 + (lane >> 4) * 4 + r;
    int tok = 4 * (lane & 15) + ni;
    outb[e] = 1.4426950408889634f * rpb[rel[row * 64 + tok] * 8 + h];
}

// ---------------------------------------------------------------------------
// LN stats pass: per-token mean / rsqrt(var) over C=256 (coalesced float4).
// Block = (b, h-pair): 256 tokens. Grid 512.
// ---------------------------------------------------------------------------
__global__ __launch_bounds__(256) void ln_stats(
    const float* __restrict__ feat, float* __restrict__ muP, float* __restrict__ rsP)
{
    __shared__ float red1[4][256];
    __shared__ float red2[4][256];
    const int blk = blockIdx.x;
    const int b = blk >> 6, h2 = blk & 63;
    const int t = threadIdx.x;
    const int c_off = t >> 6, lane = t & 63;
    const int rl = lane >> 5, w4 = (lane & 31) * 4;
    const int tok0 = rl * 128 + w4;
    const float* fp = feat + (long)b * 256 * HWC + (long)(h2 * 2 + rl) * 128 + w4;
    float s1[4] = {0.f, 0.f, 0.f, 0.f};
    float s2[4] = {0.f, 0.f, 0.f, 0.f};
#pragma unroll 4
    for (int it = 0; it < 64; it++) {
        int c = it * 4 + c_off;
        float4 f = *(const float4*)(fp + (long)c * HWC);
        s1[0] += f.x; s2[0] += f.x * f.x;
        s1[1] += f.y; s2[1] += f.y * f.y;
        s1[2] += f.z; s2[2] += f.z * f.z;
        s1[3] += f.w; s2[3] += f.w * f.w;
    }
    *(float4*)&red1[c_off][tok0] = *(float4*)s1;
    *(float4*)&red2[c_off][tok0] = *(float4*)s2;
    __syncthreads();
    float a = red1[0][t] + red1[1][t] + red1[2][t] + red1[3][t];
    float q = red2[0][t] + red2[1][t] + red2[2][t] + red2[3][t];
    float mu = a * (1.f / 256.f);
    float var = q * (1.f / 256.f) - mu * mu;
    long tg = (long)b * HWC + h2 * 256 + t;
    muP[tg] = mu;
    rsP[tg] = rsqrtf(var + 1e-5f);
}

// ---------------------------------------------------------------------------
// LN + NCHW -> window-ordered [token_win][C] transpose (affine folded away):
// xn[wid*64+n][c] = (feat - mu)*rs.  Block = (b, h-pair). Grid 512.
// ---------------------------------------------------------------------------
__global__ __launch_bounds__(256) void ln_transpose(
    const float* __restrict__ feat, const float* __restrict__ muP,
    const float* __restrict__ rsP, u16* __restrict__ xn)
{
    __shared__ u16 ct[64 * 258];
    const int blk = blockIdx.x;
    const int b = blk >> 6, h2 = blk & 63;
    const int t = threadIdx.x;
    const int c_off = t >> 6, lane = t & 63;
    const int rl = lane >> 5, w4 = (lane & 31) * 4;
    const int tok0 = rl * 128 + w4;
    const long tokg0 = (long)b * HWC + h2 * 256;
    const float4 mu4 = *(const float4*)(muP + tokg0 + tok0);
    const float4 rs4 = *(const float4*)(rsP + tokg0 + tok0);
    const float* fp = feat + (long)b * 256 * HWC + (long)(h2 * 2 + rl) * 128 + w4;
    const int koff = t & 3;

    for (int ch = 0; ch < 4; ch++) {
#pragma unroll
        for (int it = 0; it < 16; it++) {
            int c = ch * 64 + it * 4 + c_off;
            float4 f = *(const float4*)(fp + (long)c * HWC);
            uint2 pk;
            pk.x = cvtpk((f.x - mu4.x) * rs4.x, (f.y - mu4.y) * rs4.y);
            pk.y = cvtpk((f.z - mu4.z) * rs4.z, (f.w - mu4.w) * rs4.w);
            *(uint2*)&ct[(it * 4 + c_off) * 258 + tok0] = pk;
        }
        __syncthreads();
#pragma unroll
        for (int p = 0; p < 4; p++) {
            int token = p * 64 + (t >> 2);
            int hh = h2 * 2 + (token >> 7), wc = token & 127;
            long orow = ((long)b * 256 + (hh >> 3) * 16 + (wc >> 3)) * 64
                      + (hh & 7) * 8 + (wc & 7);
            union { uint4 q[2]; u16 u[16]; } pkk;
#pragma unroll
            for (int cc = 0; cc < 16; cc++)
                pkk.u[cc] = ct[(koff * 16 + cc) * 258 + token];
            u16* op = xn + orow * 256 + ch * 64 + koff * 16;
            *(uint4*)(op) = pkk.q[0];
            *(uint4*)(op + 8) = pkk.q[1];
        }
        __syncthreads();
    }
}

// ---------------------------------------------------------------------------
// Row stats over 256 bf16 cols: mu/rs per row. One wave/row, 4 rows/block.
// ---------------------------------------------------------------------------
__global__ __launch_bounds__(256) void ln2_stats(
    const u16* __restrict__ x, float* __restrict__ mu, float* __restrict__ rs)
{
    const int wave = threadIdx.x >> 6, lane = threadIdx.x & 63;
    const long row = (long)blockIdx.x * 4 + wave;
    union { uint2 v; u16 u[4]; } pk;
    pk.v = *(const uint2*)(x + row * 256 + lane * 4);
    float v0 = b2f(pk.u[0]), v1 = b2f(pk.u[1]), v2 = b2f(pk.u[2]), v3 = b2f(pk.u[3]);
    float s1 = v0 + v1 + v2 + v3;
    float s2 = v0 * v0 + v1 * v1 + v2 * v2 + v3 * v3;
    for (int off = 1; off < 64; off <<= 1) {
        s1 += __shfl_xor(s1, off);
        s2 += __shfl_xor(s2, off);
    }
    if (lane == 0) {
        float m = s1 * (1.f / 256.f);
        float var = s2 * (1.f / 256.f) - m * m;
        mu[row] = m;
        rs[row] = rsqrtf(var + 1e-5f);
    }
}

// ---------------------------------------------------------------------------
// MFMA GEMM core. 128x128 tile, BK=32, 4 waves x (64x64), swapped-operand
// (C^T) epilogue. LDS tiles [128 rows][4 chunks of 8 bf16], XOR-swizzled:
//   slot(r, c) holds logical chunk c ^ ((r>>1)&3).
// gload_lds keeps LINEAR dest; source chunk pre-swizzled; reads swizzled.
// ASRC: 0 = bf16 A via gload_lds; 1 = f32 A reg-staged (inline cvt);
//       2 = bf16 A reg-staged with LN (mu/rs per row).
// SPLIT3: N=768 qkv routing to out0/out1/out2 (each row-stride 256).
// ---------------------------------------------------------------------------
template <int EPI, bool OUTF32, int ASRC, bool SPLIT3>
__global__ __launch_bounds__(256) void gemm_core(
    const void* __restrict__ Av, const u16* __restrict__ BT,
    const float* __restrict__ bias, void* __restrict__ out0,
    void* __restrict__ out1, void* __restrict__ out2,
    const u16* __restrict__ res, const float* __restrict__ muA,
    const float* __restrict__ rsA, int M, int N, int K)
{
    __shared__ u16 As[128 * 32];
    __shared__ u16 Bs[128 * 32];
    const int tid = threadIdx.x;
    const int n0 = blockIdx.x * 128;
    const int m0 = blockIdx.y * 128;
    const int wave = tid >> 6, lane = tid & 63;
    const int wm = wave >> 1, wn = wave & 1;
    const int quad = lane >> 4, l16 = lane & 15;

    f32x4 acc[4][4];
#pragma unroll
    for (int i = 0; i < 4; i++)
#pragma unroll
        for (int j = 0; j < 4; j++) acc[i][j] = (f32x4){0.f, 0.f, 0.f, 0.f};

    // B staging: linear LDS dest (wave-uniform + lane*16B), swizzled source.
    const int srow = wave * 32 + (lane >> 2);
    const int gch = ((lane & 3) ^ ((lane >> 3) & 3)) * 8;   // source chunk
    const u16* gB = BT + (long)(n0 + srow) * K + gch;
    u16* lB = &Bs[srow * 32 + (lane & 3) * 8];

    // A staging pointers
    const u16* gA0 = nullptr; u16* lA = nullptr;
    const float* gAf = nullptr; const u16* gAh = nullptr;
    u16 *sA0 = nullptr, *sA1 = nullptr;
    float rsv = 0.f, nmu = 0.f;
    const int ar = tid >> 1;                 // reg-staged row
    const int aseg = (tid & 1) * 2;          // logical chunks aseg, aseg+1
    const int ao = (tid >> 2) & 3;           // swizzle of row ar
    if constexpr (ASRC == 0) {
        gA0 = (const u16*)Av + (long)(m0 + srow) * K + gch;
        lA = &As[srow * 32 + (lane & 3) * 8];
    } else {
        sA0 = &As[ar * 32 + (aseg ^ ao) * 8];
        sA1 = &As[ar * 32 + ((aseg + 1) ^ ao) * 8];
        if constexpr (ASRC == 1) {
            gAf = (const float*)Av + (long)(m0 + ar) * K + aseg * 8;
        } else {
            gAh = (const u16*)Av + (long)(m0 + ar) * K + aseg * 8;
            rsv = rsA[m0 + ar];
            nmu = -muA[m0 + ar] * rsv;
        }
    }

    const int rdsw = ((l16 >> 1) & 3);       // read-side swizzle

    for (int k0 = 0; k0 < K; k0 += 32) {
        float4 a0, a1, a2, a3;
        uint4 u0, u1v;
        if constexpr (ASRC == 1) {
            a0 = *(const float4*)(gAf + k0);
            a1 = *(const float4*)(gAf + k0 + 4);
            a2 = *(const float4*)(gAf + k0 + 8);
            a3 = *(const float4*)(gAf + k0 + 12);
        } else if constexpr (ASRC == 2) {
            u0 = *(const uint4*)(gAh + k0);
            u1v = *(const uint4*)(gAh + k0 + 8);
        }
        __syncthreads();
        if constexpr (ASRC == 0) {
            __builtin_amdgcn_global_load_lds(
                (const __attribute__((address_space(1))) void*)(gA0 + k0),
                (__attribute__((address_space(3))) void*)lA, 16, 0, 0);
            __builtin_amdgcn_global_load_lds(
                (const __attribute__((address_space(1))) void*)(gA0 + k0 + 16 * K),
                (__attribute__((address_space(3))) void*)(lA + 16 * 32), 16, 0, 0);
        } else if constexpr (ASRC == 1) {
            uint4 w0 = {cvtpk(a0.x, a0.y), cvtpk(a0.z, a0.w),
                        cvtpk(a1.x, a1.y), cvtpk(a1.z, a1.w)};
            uint4 w1 = {cvtpk(a2.x, a2.y), cvtpk(a2.z, a2.w),
                        cvtpk(a3.x, a3.y), cvtpk(a3.z, a3.w)};
            *(uint4*)sA0 = w0;
            *(uint4*)sA1 = w1;
        } else {
            uint4 w0 = {ln_word(u0.x, rsv, nmu), ln_word(u0.y, rsv, nmu),
                        ln_word(u0.z, rsv, nmu), ln_word(u0.w, rsv, nmu)};
            uint4 w1 = {ln_word(u1v.x, rsv, nmu), ln_word(u1v.y, rsv, nmu),
                        ln_word(u1v.z, rsv, nmu), ln_word(u1v.w, rsv, nmu)};
            *(uint4*)sA0 = w0;
            *(uint4*)sA1 = w1;
        }
        __builtin_amdgcn_global_load_lds(
            (const __attribute__((address_space(1))) void*)(gB + k0),
            (__attribute__((address_space(3))) void*)lB, 16, 0, 0);
        __builtin_amdgcn_global_load_lds(
            (const __attribute__((address_space(1))) void*)(gB + k0 + 16 * K),
            (__attribute__((address_space(3))) void*)(lB + 16 * 32), 16, 0, 0);
        __syncthreads();
        bf16x8 af[4], bfr[4];
#pragma unroll
        for (int mi = 0; mi < 4; mi++)
            af[mi] = *(const bf16x8*)&As[(wm * 64 + mi * 16 + l16) * 32 + ((quad ^ rdsw) * 8)];
#pragma unroll
        for (int ni = 0; ni < 4; ni++)
            bfr[ni] = *(const bf16x8*)&Bs[(wn * 64 + ni * 16 + l16) * 32 + ((quad ^ rdsw) * 8)];
#pragma unroll
        for (int mi = 0; mi < 4; mi++)
#pragma unroll
            for (int ni = 0; ni < 4; ni++)
                acc[mi][ni] = __builtin_amdgcn_mfma_f32_16x16x32_bf16(
                    bfr[ni], af[mi], acc[mi][ni], 0, 0, 0);
    }

    // epilogue: lane owns row = ..+l16, cols cb..cb+3 (C^T fragments)
#pragma unroll
    for (int mi = 0; mi < 4; mi++) {
        const int row = m0 + wm * 64 + mi * 16 + l16;
        long orow;
        if constexpr (EPI == EPI_WINREV) {
            int wI = row >> 6, n = row & 63;
            int bI = wI >> 8, rem = wI & 255;
            int wh = rem >> 4, wwI = rem & 15;
            orow = (long)bI * HWC + (long)((wh * 8 + (n >> 3)) * 128 + wwI * 8 + (n & 7));
        } else {
            orow = row;
        }
#pragma unroll
        for (int ni = 0; ni < 4; ni++) {
            const int cb = n0 + wn * 64 + ni * 16 + quad * 4;
            float4 bb = *(const float4*)(bias + cb);
            float v0 = acc[mi][ni][0] + bb.x;
            float v1 = acc[mi][ni][1] + bb.y;
            float v2 = acc[mi][ni][2] + bb.z;
            float v3 = acc[mi][ni][3] + bb.w;
            if constexpr (EPI == EPI_GELU) {
                v0 = gelu_f(v0); v1 = gelu_f(v1);
                v2 = gelu_f(v2); v3 = gelu_f(v3);
            }
            if constexpr (EPI == EPI_WINREV || EPI == EPI_ADD) {
                uint2 rr = *(const uint2*)(res + orow * (long)N + cb);
                v0 += b2f((u16)(rr.x & 0xffff));
                v1 += b2f((u16)(rr.x >> 16));
                v2 += b2f((u16)(rr.y & 0xffff));
                v3 += b2f((u16)(rr.y >> 16));
            }
            if constexpr (SPLIT3) {
                u16* ob = (u16*)(n0 < 256 ? out0 : n0 < 512 ? out1 : out2);
                uint2 o;
                o.x = cvtpk(v0, v1);
                o.y = cvtpk(v2, v3);
                *(uint2*)(ob + orow * 256L + (cb & 255)) = o;
            } else if constexpr (OUTF32) {
                float4 o = {v0, v1, v2, v3};
                *(float4*)((float*)out0 + orow * (long)N + cb) = o;
            } else {
                uint2 o;
                o.x = cvtpk(v0, v1);
                o.y = cvtpk(v2, v3);
                *(uint2*)((u16*)out0 + orow * (long)N + cb) = o;
            }
        }
    }
}

// ---------------------------------------------------------------------------
// Window attention (window-ordered tokens): one wave per (window, head).
// Grid 4096 x 256 thr. Base-2 no-max softmax, sigma-permuted K columns,
// O^T-swapped PV, packed stores. LDS 51200B -> 3 blocks/CU, barrier-free.
// O written IN-PLACE over qb (disjoint column ownership).
// ---------------------------------------------------------------------------
__global__ __launch_bounds__(256, 3) void attn_kernel(
    const u16* __restrict__ qb, const u16* __restrict__ kb,
    const u16* __restrict__ vb, const float* __restrict__ biasp,
    u16* __restrict__ ob)
{
    __shared__ u16 lds[4 * 6400];
    const int wave = threadIdx.x >> 6, lane = threadIdx.x & 63;
    const int quad = lane >> 4, l16 = lane & 15;
    const int w = blockIdx.x >> 1;
    const int h = ((blockIdx.x & 1) << 2) + wave;
    u16* Pl = lds + wave * 6400;       // [2 ks][64 m][32 slots]
    u16* VT = Pl + 4096;               // [32 dims][72], slot-permuted V^T
    const long base = (long)w * 64 * 256 + h * 32;

    // ---- load Q fragments and sigma-permuted K fragments ----
    bf16x8 aq[4], bk4[4];
#pragma unroll
    for (int mi = 0; mi < 4; mi++)
        aq[mi] = *(const bf16x8*)(qb + base + (long)(mi * 16 + l16) * 256 + quad * 8);
#pragma unroll
    for (int ni = 0; ni < 4; ni++)
        bk4[ni] = *(const bf16x8*)(kb + base + (long)(4 * l16 + ni) * 256 + quad * 8);

    // ---- stage V^T with slot permutation (lane <-> token) ----
    {
        const int t = lane;
        const int s = ((t >> 4) & 1) * 32 + ((t >> 2) & 3) * 8 + (t >> 5) * 4 + (t & 3);
        const u16* vp = vb + base + (long)t * 256;
        union { uint4 v; u16 u[8]; } p0, p1, p2, p3;
        p0.v = *(const uint4*)(vp);
        p1.v = *(const uint4*)(vp + 8);
        p2.v = *(const uint4*)(vp + 16);
        p3.v = *(const uint4*)(vp + 24);
#pragma unroll
        for (int j = 0; j < 8; j++) {
            VT[j * 72 + s]        = p0.u[j];
            VT[(8 + j) * 72 + s]  = p1.u[j];
            VT[(16 + j) * 72 + s] = p2.u[j];
            VT[(24 + j) * 72 + s] = p3.u[j];
        }
    }

    // ---- S = Q @ K^T (columns sigma-permuted) ----
    f32x4 s[4][4];
#pragma unroll
    for (int i = 0; i < 4; i++)
#pragma unroll
        for (int j = 0; j < 4; j++) s[i][j] = (f32x4){0.f, 0.f, 0.f, 0.f};
    __builtin_amdgcn_s_setprio(1);
#pragma unroll
    for (int mi = 0; mi < 4; mi++)
#pragma unroll
        for (int ni = 0; ni < 4; ni++)
            s[mi][ni] = __builtin_amdgcn_mfma_f32_16x16x32_bf16(aq[mi], bk4[ni], s[mi][ni], 0, 0, 0);
    __builtin_amdgcn_s_setprio(0);

    // ---- softmax, base-2 domain, no max subtraction ----
    const float* bp = biasp + h * 4096;
    const float SC2 = 0.17677669529663687f * 1.4426950408889634f;  // scale*log2e
    const int pq = l16 & 3, pks = (l16 >> 2) & 1, ph = l16 >> 3;
#pragma unroll
    for (int mi = 0; mi < 4; mi++) {
        f32x4 bb[4];
#pragma unroll
        for (int ni = 0; ni < 4; ni++)
            bb[ni] = *(const f32x4*)(bp + ((mi * 4 + ni) << 8) + lane * 4);
#pragma unroll
        for (int r = 0; r < 4; r++) {
            float p[4];
#pragma unroll
            for (int ni = 0; ni < 4; ni++)
                p[ni] = __builtin_amdgcn_exp2f(s[mi][ni][r] * SC2 + bb[ni][r]);
            float sum = (p[0] + p[1]) + (p[2] + p[3]);
            for (int off = 1; off < 16; off <<= 1) sum += __shfl_xor(sum, off);
            float inv = __builtin_amdgcn_rcpf(sum);
            int mrow = mi * 16 + quad * 4 + r;
            uint2 w2;
            w2.x = cvtpk(p[0] * inv, p[1] * inv);
            w2.y = cvtpk(p[2] * inv, p[3] * inv);
            *(uint2*)&Pl[pks * 2048 + mrow * 32 + pq * 8 + ph * 4] = w2;
        }
    }

    // ---- O^T = V^T @ P^T  (M=32 dims, N=64 query rows, K=64 tokens) ----
    f32x4 o4[2][4];
#pragma unroll
    for (int i = 0; i < 2; i++)
#pragma unroll
        for (int j = 0; j < 4; j++) o4[i][j] = (f32x4){0.f, 0.f, 0.f, 0.f};
#pragma unroll
    for (int ks = 0; ks < 2; ks++) {
        bf16x8 at[2], pb[4];
#pragma unroll
        for (int mi = 0; mi < 2; mi++)
            at[mi] = *(const bf16x8*)&VT[(mi * 16 + l16) * 72 + ks * 32 + quad * 8];
#pragma unroll
        for (int nt = 0; nt < 4; nt++)
            pb[nt] = *(const bf16x8*)&Pl[ks * 2048 + (nt * 16 + l16) * 32 + quad * 8];
        __builtin_amdgcn_s_setprio(1);
#pragma unroll
        for (int mi = 0; mi < 2; mi++)
#pragma unroll
            for (int nt = 0; nt < 4; nt++)
                o4[mi][nt] = __builtin_amdgcn_mfma_f32_16x16x32_bf16(at[mi], pb[nt], o4[mi][nt], 0, 0, 0);
        __builtin_amdgcn_s_setprio(0);
    }

    // ---- store O (packed 4 dims/lane, in-place over this wave's q cols) ----
#pragma unroll
    for (int nt = 0; nt < 4; nt++)
#pragma unroll
        for (int mi = 0; mi < 2; mi++) {
            uint2 w2;
            w2.x = cvtpk(o4[mi][nt][0], o4[mi][nt][1]);
            w2.y = cvtpk(o4[mi][nt][2], o4[mi][nt][3]);
            *(uint2*)(ob + base + (long)(nt * 16 + l16) * 256 + mi * 16 + quad * 4) = w2;
        }
}

// ---------------------------------------------------------------------------
extern "C" void kernel_launch(void* const* d_in, const int* in_sizes, int n_in,
                              void* d_out, int out_size, void* d_ws, size_t ws_size,
                              hipStream_t stream)
{
    (void)in_sizes; (void)n_in; (void)out_size; (void)ws_size;
    const float* x    = (const float*)d_in[0];
    const float* feat = (const float*)d_in[1];
    const float* Wq = (const float*)d_in[2];   const float* bq = (const float*)d_in[3];
    const float* Wk = (const float*)d_in[4];   const float* bk = (const float*)d_in[5];
    const float* Wv = (const float*)d_in[6];   const float* bv = (const float*)d_in[7];
    const float* Wo = (const float*)d_in[8];   const float* bo = (const float*)d_in[9];
    const float* rpb = (const float*)d_in[10];
    const float* g1 = (const float*)d_in[11];  const float* be1 = (const float*)d_in[12];
    const float* g2 = (const float*)d_in[13];  const float* be2 = (const float*)d_in[14];
    const float* Wm1 = (const float*)d_in[15]; const float* bm1 = (const float*)d_in[16];
    const float* Wm2 = (const float*)d_in[17]; const float* bm2 = (const float*)d_in[18];
    const float* Wu1 = (const float*)d_in[19]; const float* bu1 = (const float*)d_in[20];
    const float* Wu2 = (const float*)d_in[21]; const float* bu2 = (const float*)d_in[22];
    const int* rel = (const int*)d_in[23];
    float* outp = (float*)d_out;

    char* ws = (char*)d_ws;
    u16* WqT  = (u16*)(ws);          // 768x256 contiguous (q,k,v) for merged GEMM
    u16* WkT  = WqT + 65536;
    u16* WvT  = WkT + 65536;
    u16* WoT  = WvT + 65536;
    u16* Wu1T = WoT + 65536;
    u16* Wu2T = Wu1T + 65536;
    u16* Wm1T = Wu2T + 65536;    // 1024 x 256
    u16* Wm2T = Wm1T + 262144;   // 256 x 1024
    float* biasf = (float*)(ws + 1835008);     // 128 KB rpb prepack
    float* bqkv  = (float*)(ws + 1966080);     // 768 f32 folded qkv bias
    float* bm1f  = (float*)(ws + 1970176);     // 1024 f32 folded mlp bias
    const long MB = 1024L * 1024;
    u16* S0 = (u16*)(ws + 2 * MB);      // q -> O -> mlp stats
    u16* S1 = (u16*)(ws + 66 * MB);     // k -> un -> hch
    u16* S2 = (u16*)(ws + 130 * MB);    // v -> u1h -> x2
    u16* xn  = (u16*)d_out;             // bf16 xn in first half of f32 d_out
    float* muP = (float*)((char*)d_out + 96 * MB);   // LN1 stats (dead early)
    float* rsP = (float*)((char*)d_out + 97 * MB);
    u16* qb  = S0;
    u16* kb  = S1;
    u16* vb  = S2;
    u16* O   = S0;     // attn output in-place over q
    u16* u1h = S2;     // unary hidden (v dead after attn)
    u16* un  = S1;     // unary output (k dead after attn)
    u16* x2  = S2;     // trunk (u1h dead after unary GEMM2)
    float* mu2 = (float*)S0;            // MLP LN stats (O dead after o-proj)
    float* rs2 = mu2 + MTOK;
    u16* hch = S1;     // mlp hidden chunk (un dead after o-proj)

    const dim3 blk(256);

    // weight transposes (+LN-gamma fold) + bias folds + rpb prepack
    transpose_f32_bf16<<<dim3(8, 8), blk, 0, stream>>>(Wq, g1, WqT, 256, 256);
    transpose_f32_bf16<<<dim3(8, 8), blk, 0, stream>>>(Wk, g1, WkT, 256, 256);
    transpose_f32_bf16<<<dim3(8, 8), blk, 0, stream>>>(Wv, g1, WvT, 256, 256);
    transpose_f32_bf16<<<dim3(8, 8), blk, 0, stream>>>(Wo, nullptr, WoT, 256, 256);
    transpose_f32_bf16<<<dim3(8, 8), blk, 0, stream>>>(Wu1, nullptr, Wu1T, 256, 256);
    transpose_f32_bf16<<<dim3(8, 8), blk, 0, stream>>>(Wu2, nullptr, Wu2T, 256, 256);
    transpose_f32_bf16<<<dim3(8, 32), blk, 0, stream>>>(Wm1, g2, Wm1T, 256, 1024);
    transpose_f32_bf16<<<dim3(32, 8), blk, 0, stream>>>(Wm2, nullptr, Wm2T, 1024, 256);
    bias_fold<<<dim3(1), blk, 0, stream>>>(Wq, bq, be1, bqkv, 256, 256);
    bias_fold<<<dim3(1), blk, 0, stream>>>(Wk, bk, be1, bqkv + 256, 256, 256);
    bias_fold<<<dim3(1), blk, 0, stream>>>(Wv, bv, be1, bqkv + 512, 256, 256);
    bias_fold<<<dim3(4), blk, 0, stream>>>(Wm1, bm1, be2, bm1f, 256, 1024);
    rpb_gather<<<dim3(128), blk, 0, stream>>>(rpb, rel, biasf);

    // LN1: stats + windowed transpose, feat -> xn
    ln_stats<<<dim3(512), blk, 0, stream>>>(feat, muP, rsP);
    ln_transpose<<<dim3(512), blk, 0, stream>>>(feat, muP, rsP, xn);

    // merged qkv projection (N=768, 3-way routed output)
    gemm_core<EPI_NONE, false, 0, true><<<dim3(6, 1024), blk, 0, stream>>>(
        xn, WqT, bqkv, qb, kb, vb, nullptr, nullptr, nullptr, MTOK, 768, 256);

    // window attention (O in-place over qb); k,v dead after
    attn_kernel<<<dim3(4096), blk, 0, stream>>>(qb, kb, vb, biasf, O);

    // unary path: gelu(x@Wu1+bu1) -> u1h (f32 A inline-cvt); @Wu2+bu2 -> un
    gemm_core<EPI_GELU, false, 1, false><<<dim3(2, 1024), blk, 0, stream>>>(
        x, Wu1T, bu1, u1h, nullptr, nullptr, nullptr, nullptr, nullptr, MTOK, 256, 256);
    gemm_core<EPI_NONE, false, 0, false><<<dim3(2, 1024), blk, 0, stream>>>(
        u1h, Wu2T, bu2, un, nullptr, nullptr, nullptr, nullptr, nullptr, MTOK, 256, 256);

    // o-proj + window reverse + add unary -> x2 (raw order)
    gemm_core<EPI_WINREV, false, 0, false><<<dim3(2, 1024), blk, 0, stream>>>(
        O, WoT, bo, x2, nullptr, nullptr, un, nullptr, nullptr, MTOK, 256, 256);

    // MLP: row stats once, then 4 chunks of 32768:
    //   out = x2 + gelu(((x2-mu)*rs)@Wm1'+bm1')@Wm2+bm2
    ln2_stats<<<dim3(32768), blk, 0, stream>>>(x2, mu2, rs2);
    for (int ch = 0; ch < 4; ch++) {
        const u16* x2c = x2 + (long)ch * 32768 * 256;
        float* outc = outp + (long)ch * 32768 * 256;
        gemm_core<EPI_GELU, false, 2, false><<<dim3(8, 256), blk, 0, stream>>>(
            x2c, Wm1T, bm1f, hch, nullptr, nullptr, nullptr,
            mu2 + (long)ch * 32768, rs2 + (long)ch * 32768, 32768, 1024, 256);
        gemm_core<EPI_ADD, true, 0, false><<<dim3(2, 256), blk, 0, stream>>>(
            hch, Wm2T, bm2, outc, nullptr, nullptr, x2c, nullptr, nullptr, 32768, 256, 1024);
    }
}

// Round 5
// 1303.938 us; speedup vs baseline: 1.0376x; 1.0376x over previous
//
#include <hip/hip_runtime.h>
#include <cmath>

// ---------------------------------------------------------------------------
// NeWCRFBlock: unary MLP + window-attention + MLP, B=8 C=256 H=W=128 WS=8 NH=8
// Round-7: resubmission of round-6 kernel (bench infra failed; no defect
// found on audit). Changes vs last MEASURED kernel (round-5/155us-QKV):
//   * gemm_core K-loop -> 2-phase double-buffered pipeline (T3 minimum):
//     stage tile t+1 BEFORE computing tile t; one barrier per K-step
//     (safe: __syncthreads drains vmcnt+lgkmcnt on gfx950).
//   * XCD-chunked bijective block swizzle (T1) on all GEMMs: blocks sharing
//     an A tile land on the same XCD -> kills the 3x A over-fetch seen in
//     round-3 counters (FETCH 198MB for 64MB A).
// Carried: T2 swizzled LDS (conflicts==0 verified), C^T packed epilogue,
//   window token order, two-pass LN1, LN affine folds, fused MLP LN,
//   merged QKV, attn kernel (round-0-validated structure).
// ---------------------------------------------------------------------------

typedef unsigned short u16;
typedef unsigned int u32;
typedef __bf16 bf16x8 __attribute__((ext_vector_type(8)));
typedef float f32x4 __attribute__((ext_vector_type(4)));

#define EPI_NONE 0
#define EPI_GELU 1
#define EPI_WINREV 2
#define EPI_ADD 3

#define MTOK 131072
#define CC 256
#define HWC 16384

__device__ __forceinline__ float b2f(u16 u) {
    union { u32 i; float f; } x; x.i = ((u32)u) << 16; return x.f;
}
__device__ __forceinline__ u16 f2b(float f) {
    union { float f; u32 i; } x; x.f = f;
    u32 r = x.i + 0x7fffu + ((x.i >> 16) & 1u);
    return (u16)(r >> 16);
}
__device__ __forceinline__ u32 cvtpk(float lo, float hi) {
    u32 r;
    asm("v_cvt_pk_bf16_f32 %0, %1, %2" : "=v"(r) : "v"(lo), "v"(hi));
    return r;
}
__device__ __forceinline__ float gelu_f(float v) {
    return 0.5f * v * (1.0f + erff(v * 0.7071067811865475f));
}
// (bf16 pair word) -> LN'd bf16 pair word: y = (x - mu)*rs = fma(x, rs, -mu*rs)
__device__ __forceinline__ u32 ln_word(u32 w, float rs, float nmurs) {
    union { u32 i; float f; } lo, hi;
    lo.i = w << 16; hi.i = w & 0xffff0000u;
    return cvtpk(fmaf(lo.f, rs, nmurs), fmaf(hi.f, rs, nmurs));
}

// ---------------------------------------------------------------------------
// Weight transpose + optional per-row scale + downcast:
//   dst_bf16[n*K+k] = src_f32[k*N+n] * (scale ? scale[k] : 1)
// ---------------------------------------------------------------------------
__global__ __launch_bounds__(256) void transpose_f32_bf16(
    const float* __restrict__ src, const float* __restrict__ scale,
    u16* __restrict__ dst, int K, int N)
{
    __shared__ float t[32][33];
    const int k0 = blockIdx.x * 32, n0 = blockIdx.y * 32;
    const int tx = threadIdx.x & 31, ty = threadIdx.x >> 5;
    for (int i = ty; i < 32; i += 8) {
        float sc = scale ? scale[k0 + i] : 1.0f;
        t[i][tx] = src[(long)(k0 + i) * N + n0 + tx] * sc;
    }
    __syncthreads();
    for (int i = ty; i < 32; i += 8)
        dst[(long)(n0 + i) * K + k0 + tx] = f2b(t[tx][i]);
}

// ---------------------------------------------------------------------------
// Folded bias: out[n] = b[n] + sum_k beta[k] * W[k*N+n]
// ---------------------------------------------------------------------------
__global__ __launch_bounds__(256) void bias_fold(
    const float* __restrict__ W, const float* __restrict__ b,
    const float* __restrict__ beta, float* __restrict__ out, int K, int N)
{
    int n = blockIdx.x * 256 + threadIdx.x;
    if (n >= N) return;
    float s = b[n];
    for (int k = 0; k < K; k++) s += beta[k] * W[(long)k * N + n];
    out[n] = s;
}

// ---------------------------------------------------------------------------
// Bias prepack for attn (f32), MFMA C-fragment layout, sigma-permuted keys.
// ---------------------------------------------------------------------------
__global__ __launch_bounds__(256) void rpb_gather(
    const float* __restrict__ rpb, const int* __restrict__ rel, float* __restrict__ outb)
{
    int e = blockIdx.x * 256 + threadIdx.x;   // 32768 total
    int h = e >> 12, idx = e & 4095;
    int mi = idx >> 10, ni = (idx >> 8) & 3, lane = (idx >> 2) & 63, r = idx & 3;
    int row = mi * 16 + (lane >> 4) * 4 + r;
    int tok = 4 * (lane & 15) + ni;
    outb[e] = 1.4426950408889634f * rpb[rel[row * 64 + tok] * 8 + h];
}

// ---------------------------------------------------------------------------
// LN stats pass: per-token mean / rsqrt(var) over C=256 (coalesced float4).
// Block = (b, h-pair): 256 tokens. Grid 512.
// ---------------------------------------------------------------------------
__global__ __launch_bounds__(256) void ln_stats(
    const float* __restrict__ feat, float* __restrict__ muP, float* __restrict__ rsP)
{
    __shared__ float red1[4][256];
    __shared__ float red2[4][256];
    const int blk = blockIdx.x;
    const int b = blk >> 6, h2 = blk & 63;
    const int t = threadIdx.x;
    const int c_off = t >> 6, lane = t & 63;
    const int rl = lane >> 5, w4 = (lane & 31) * 4;
    const int tok0 = rl * 128 + w4;
    const float* fp = feat + (long)b * 256 * HWC + (long)(h2 * 2 + rl) * 128 + w4;
    float s1[4] = {0.f, 0.f, 0.f, 0.f};
    float s2[4] = {0.f, 0.f, 0.f, 0.f};
#pragma unroll 4
    for (int it = 0; it < 64; it++) {
        int c = it * 4 + c_off;
        float4 f = *(const float4*)(fp + (long)c * HWC);
        s1[0] += f.x; s2[0] += f.x * f.x;
        s1[1] += f.y; s2[1] += f.y * f.y;
        s1[2] += f.z; s2[2] += f.z * f.z;
        s1[3] += f.w; s2[3] += f.w * f.w;
    }
    *(float4*)&red1[c_off][tok0] = *(float4*)s1;
    *(float4*)&red2[c_off][tok0] = *(float4*)s2;
    __syncthreads();
    float a = red1[0][t] + red1[1][t] + red1[2][t] + red1[3][t];
    float q = red2[0][t] + red2[1][t] + red2[2][t] + red2[3][t];
    float mu = a * (1.f / 256.f);
    float var = q * (1.f / 256.f) - mu * mu;
    long tg = (long)b * HWC + h2 * 256 + t;
    muP[tg] = mu;
    rsP[tg] = rsqrtf(var + 1e-5f);
}

// ---------------------------------------------------------------------------
// LN + NCHW -> window-ordered [token_win][C] transpose (affine folded away):
// xn[wid*64+n][c] = (feat - mu)*rs.  Block = (b, h-pair). Grid 512.
// ---------------------------------------------------------------------------
__global__ __launch_bounds__(256) void ln_transpose(
    const float* __restrict__ feat, const float* __restrict__ muP,
    const float* __restrict__ rsP, u16* __restrict__ xn)
{
    __shared__ u16 ct[64 * 258];
    const int blk = blockIdx.x;
    const int b = blk >> 6, h2 = blk & 63;
    const int t = threadIdx.x;
    const int c_off = t >> 6, lane = t & 63;
    const int rl = lane >> 5, w4 = (lane & 31) * 4;
    const int tok0 = rl * 128 + w4;
    const long tokg0 = (long)b * HWC + h2 * 256;
    const float4 mu4 = *(const float4*)(muP + tokg0 + tok0);
    const float4 rs4 = *(const float4*)(rsP + tokg0 + tok0);
    const float* fp = feat + (long)b * 256 * HWC + (long)(h2 * 2 + rl) * 128 + w4;
    const int koff = t & 3;

    for (int ch = 0; ch < 4; ch++) {
#pragma unroll
        for (int it = 0; it < 16; it++) {
            int c = ch * 64 + it * 4 + c_off;
            float4 f = *(const float4*)(fp + (long)c * HWC);
            uint2 pk;
            pk.x = cvtpk((f.x - mu4.x) * rs4.x, (f.y - mu4.y) * rs4.y);
            pk.y = cvtpk((f.z - mu4.z) * rs4.z, (f.w - mu4.w) * rs4.w);
            *(uint2*)&ct[(it * 4 + c_off) * 258 + tok0] = pk;
        }
        __syncthreads();
#pragma unroll
        for (int p = 0; p < 4; p++) {
            int token = p * 64 + (t >> 2);
            int hh = h2 * 2 + (token >> 7), wc = token & 127;
            long orow = ((long)b * 256 + (hh >> 3) * 16 + (wc >> 3)) * 64
                      + (hh & 7) * 8 + (wc & 7);
            union { uint4 q[2]; u16 u[16]; } pkk;
#pragma unroll
            for (int cc = 0; cc < 16; cc++)
                pkk.u[cc] = ct[(koff * 16 + cc) * 258 + token];
            u16* op = xn + orow * 256 + ch * 64 + koff * 16;
            *(uint4*)(op) = pkk.q[0];
            *(uint4*)(op + 8) = pkk.q[1];
        }
        __syncthreads();
    }
}

// ---------------------------------------------------------------------------
// Row stats over 256 bf16 cols: mu/rs per row. One wave/row, 4 rows/block.
// ---------------------------------------------------------------------------
__global__ __launch_bounds__(256) void ln2_stats(
    const u16* __restrict__ x, float* __restrict__ mu, float* __restrict__ rs)
{
    const int wave = threadIdx.x >> 6, lane = threadIdx.x & 63;
    const long row = (long)blockIdx.x * 4 + wave;
    union { uint2 v; u16 u[4]; } pk;
    pk.v = *(const uint2*)(x + row * 256 + lane * 4);
    float v0 = b2f(pk.u[0]), v1 = b2f(pk.u[1]), v2 = b2f(pk.u[2]), v3 = b2f(pk.u[3]);
    float s1 = v0 + v1 + v2 + v3;
    float s2 = v0 * v0 + v1 * v1 + v2 * v2 + v3 * v3;
    for (int off = 1; off < 64; off <<= 1) {
        s1 += __shfl_xor(s1, off);
        s2 += __shfl_xor(s2, off);
    }
    if (lane == 0) {
        float m = s1 * (1.f / 256.f);
        float var = s2 * (1.f / 256.f) - m * m;
        mu[row] = m;
        rs[row] = rsqrtf(var + 1e-5f);
    }
}

// ---------------------------------------------------------------------------
// MFMA GEMM core. 128x128 tile, BK=32, 4 waves x (64x64), swapped-operand
// (C^T) epilogue. 2-phase double-buffered K-loop: stage t+1 before compute t,
// ONE barrier per K-step (gfx950 __syncthreads drains vmcnt+lgkmcnt).
// LDS XOR-swizzled (linear gload_lds dest + pre-swizzled global source +
// swizzled frag reads).
// ASRC: 0 = bf16 A via gload_lds; 1 = f32 A reg-staged (inline cvt);
//       2 = bf16 A reg-staged with LN (mu/rs per row).
// SPLIT3: N=768 qkv routing to out0/out1/out2 (each row-stride 256).
// 1-D grid, XCD-chunked bijective swizzle (requires gridDim.x % 8 == 0).
// ---------------------------------------------------------------------------
template <int EPI, bool OUTF32, int ASRC, bool SPLIT3>
__global__ __launch_bounds__(256) void gemm_core(
    const void* __restrict__ Av, const u16* __restrict__ BT,
    const float* __restrict__ bias, void* __restrict__ out0,
    void* __restrict__ out1, void* __restrict__ out2,
    const u16* __restrict__ res, const float* __restrict__ muA,
    const float* __restrict__ rsA, int M, int N, int K, int nx)
{
    __shared__ u16 As[2][128 * 32];
    __shared__ u16 Bs[2][128 * 32];
    const int tid = threadIdx.x;
    // XCD-chunked swizzle: consecutive logical blocks (sharing an A tile)
    // land on the same XCD (hardware round-robins blockIdx % 8 across XCDs).
    const int nwg = gridDim.x;
    const int lg = ((int)blockIdx.x & 7) * (nwg >> 3) + ((int)blockIdx.x >> 3);
    const int n0 = (lg % nx) * 128;
    const int m0 = (lg / nx) * 128;
    const int wave = tid >> 6, lane = tid & 63;
    const int wm = wave >> 1, wn = wave & 1;
    const int quad = lane >> 4, l16 = lane & 15;

    f32x4 acc[4][4];
#pragma unroll
    for (int i = 0; i < 4; i++)
#pragma unroll
        for (int j = 0; j < 4; j++) acc[i][j] = (f32x4){0.f, 0.f, 0.f, 0.f};

    // B staging: linear LDS dest (wave-uniform + lane*16B), swizzled source.
    const int srow = wave * 32 + (lane >> 2);
    const int gch = ((lane & 3) ^ ((lane >> 3) & 3)) * 8;   // source chunk
    const u16* gB = BT + (long)(n0 + srow) * K + gch;
    const int lBoff = srow * 32 + (lane & 3) * 8;

    // A staging pointers
    const u16* gA0 = nullptr;
    const float* gAf = nullptr; const u16* gAh = nullptr;
    int sA0off = 0, sA1off = 0;
    float rsv = 0.f, nmu = 0.f;
    const int ar = tid >> 1;                 // reg-staged row
    const int aseg = (tid & 1) * 2;          // logical chunks aseg, aseg+1
    const int ao = (tid >> 2) & 3;           // swizzle of row ar
    if constexpr (ASRC == 0) {
        gA0 = (const u16*)Av + (long)(m0 + srow) * K + gch;
    } else {
        sA0off = ar * 32 + (aseg ^ ao) * 8;
        sA1off = ar * 32 + ((aseg + 1) ^ ao) * 8;
        if constexpr (ASRC == 1) {
            gAf = (const float*)Av + (long)(m0 + ar) * K + aseg * 8;
        } else {
            gAh = (const u16*)Av + (long)(m0 + ar) * K + aseg * 8;
            rsv = rsA[m0 + ar];
            nmu = -muA[m0 + ar] * rsv;
        }
    }

    const int rdsw = ((l16 >> 1) & 3);       // read-side swizzle

    // ---- prologue: stage tile k0=0 into buffer 0 ----
    if constexpr (ASRC == 0) {
        __builtin_amdgcn_global_load_lds(
            (const __attribute__((address_space(1))) void*)(gA0),
            (__attribute__((address_space(3))) void*)&As[0][lBoff], 16, 0, 0);
        __builtin_amdgcn_global_load_lds(
            (const __attribute__((address_space(1))) void*)(gA0 + 16 * K),
            (__attribute__((address_space(3))) void*)&As[0][lBoff + 16 * 32], 16, 0, 0);
    } else if constexpr (ASRC == 1) {
        float4 a0 = *(const float4*)(gAf);
        float4 a1 = *(const float4*)(gAf + 4);
        float4 a2 = *(const float4*)(gAf + 8);
        float4 a3 = *(const float4*)(gAf + 12);
        uint4 w0 = {cvtpk(a0.x, a0.y), cvtpk(a0.z, a0.w),
                    cvtpk(a1.x, a1.y), cvtpk(a1.z, a1.w)};
        uint4 w1 = {cvtpk(a2.x, a2.y), cvtpk(a2.z, a2.w),
                    cvtpk(a3.x, a3.y), cvtpk(a3.z, a3.w)};
        *(uint4*)&As[0][sA0off] = w0;
        *(uint4*)&As[0][sA1off] = w1;
    } else {
        uint4 u0 = *(const uint4*)(gAh);
        uint4 u1v = *(const uint4*)(gAh + 8);
        uint4 w0 = {ln_word(u0.x, rsv, nmu), ln_word(u0.y, rsv, nmu),
                    ln_word(u0.z, rsv, nmu), ln_word(u0.w, rsv, nmu)};
        uint4 w1 = {ln_word(u1v.x, rsv, nmu), ln_word(u1v.y, rsv, nmu),
                    ln_word(u1v.z, rsv, nmu), ln_word(u1v.w, rsv, nmu)};
        *(uint4*)&As[0][sA0off] = w0;
        *(uint4*)&As[0][sA1off] = w1;
    }
    __builtin_amdgcn_global_load_lds(
        (const __attribute__((address_space(1))) void*)(gB),
        (__attribute__((address_space(3))) void*)&Bs[0][lBoff], 16, 0, 0);
    __builtin_amdgcn_global_load_lds(
        (const __attribute__((address_space(1))) void*)(gB + 16 * K),
        (__attribute__((address_space(3))) void*)&Bs[0][lBoff + 16 * 32], 16, 0, 0);
    __syncthreads();

    int cur = 0;
#pragma unroll 2
    for (int k0 = 0; k0 < K; k0 += 32) {
        const int kn = k0 + 32;
        const bool hn = kn < K;
        float4 a0, a1, a2, a3;
        uint4 u0, u1v;
        // (a) issue next-tile staging EARLY (overlaps ds_read + MFMA below)
        if (hn) {
            if constexpr (ASRC == 0) {
                __builtin_amdgcn_global_load_lds(
                    (const __attribute__((address_space(1))) void*)(gA0 + kn),
                    (__attribute__((address_space(3))) void*)&As[cur ^ 1][lBoff], 16, 0, 0);
                __builtin_amdgcn_global_load_lds(
                    (const __attribute__((address_space(1))) void*)(gA0 + kn + 16 * K),
                    (__attribute__((address_space(3))) void*)&As[cur ^ 1][lBoff + 16 * 32], 16, 0, 0);
            } else if constexpr (ASRC == 1) {
                a0 = *(const float4*)(gAf + kn);
                a1 = *(const float4*)(gAf + kn + 4);
                a2 = *(const float4*)(gAf + kn + 8);
                a3 = *(const float4*)(gAf + kn + 12);
            } else if constexpr (ASRC == 2) {
                u0 = *(const uint4*)(gAh + kn);
                u1v = *(const uint4*)(gAh + kn + 8);
            }
            __builtin_amdgcn_global_load_lds(
                (const __attribute__((address_space(1))) void*)(gB + kn),
                (__attribute__((address_space(3))) void*)&Bs[cur ^ 1][lBoff], 16, 0, 0);
            __builtin_amdgcn_global_load_lds(
                (const __attribute__((address_space(1))) void*)(gB + kn + 16 * K),
                (__attribute__((address_space(3))) void*)&Bs[cur ^ 1][lBoff + 16 * 32], 16, 0, 0);
        }
        // (b) ds_read fragments of current tile
        bf16x8 af[4], bfr[4];
#pragma unroll
        for (int mi = 0; mi < 4; mi++)
            af[mi] = *(const bf16x8*)&As[cur][(wm * 64 + mi * 16 + l16) * 32 + ((quad ^ rdsw) * 8)];
#pragma unroll
        for (int ni = 0; ni < 4; ni++)
            bfr[ni] = *(const bf16x8*)&Bs[cur][(wn * 64 + ni * 16 + l16) * 32 + ((quad ^ rdsw) * 8)];
        // (c) MFMA
#pragma unroll
        for (int mi = 0; mi < 4; mi++)
#pragma unroll
            for (int ni = 0; ni < 4; ni++)
                acc[mi][ni] = __builtin_amdgcn_mfma_f32_16x16x32_bf16(
                    bfr[ni], af[mi], acc[mi][ni], 0, 0, 0);
        // (d) reg-staged A: convert + write next tile into buf^1
        if (hn) {
            if constexpr (ASRC == 1) {
                uint4 w0 = {cvtpk(a0.x, a0.y), cvtpk(a0.z, a0.w),
                            cvtpk(a1.x, a1.y), cvtpk(a1.z, a1.w)};
                uint4 w1 = {cvtpk(a2.x, a2.y), cvtpk(a2.z, a2.w),
                            cvtpk(a3.x, a3.y), cvtpk(a3.z, a3.w)};
                *(uint4*)&As[cur ^ 1][sA0off] = w0;
                *(uint4*)&As[cur ^ 1][sA1off] = w1;
            } else if constexpr (ASRC == 2) {
                uint4 w0 = {ln_word(u0.x, rsv, nmu), ln_word(u0.y, rsv, nmu),
                            ln_word(u0.z, rsv, nmu), ln_word(u0.w, rsv, nmu)};
                uint4 w1 = {ln_word(u1v.x, rsv, nmu), ln_word(u1v.y, rsv, nmu),
                            ln_word(u1v.z, rsv, nmu), ln_word(u1v.w, rsv, nmu)};
                *(uint4*)&As[cur ^ 1][sA0off] = w0;
                *(uint4*)&As[cur ^ 1][sA1off] = w1;
            }
        }
        // (e) single barrier: publishes buf^1, closes reads of buf[cur]
        __syncthreads();
        cur ^= 1;
    }

    // epilogue: lane owns row = ..+l16, cols cb..cb+3 (C^T fragments)
#pragma unroll
    for (int mi = 0; mi < 4; mi++) {
        const int row = m0 + wm * 64 + mi * 16 + l16;
        long orow;
        if constexpr (EPI == EPI_WINREV) {
            int wI = row >> 6, n = row & 63;
            int bI = wI >> 8, rem = wI & 255;
            int wh = rem >> 4, wwI = rem & 15;
            orow = (long)bI * HWC + (long)((wh * 8 + (n >> 3)) * 128 + wwI * 8 + (n & 7));
        } else {
            orow = row;
        }
#pragma unroll
        for (int ni = 0; ni < 4; ni++) {
            const int cb = n0 + wn * 64 + ni * 16 + quad * 4;
            float4 bb = *(const float4*)(bias + cb);
            float v0 = acc[mi][ni][0] + bb.x;
            float v1 = acc[mi][ni][1] + bb.y;
            float v2 = acc[mi][ni][2] + bb.z;
            float v3 = acc[mi][ni][3] + bb.w;
            if constexpr (EPI == EPI_GELU) {
                v0 = gelu_f(v0); v1 = gelu_f(v1);
                v2 = gelu_f(v2); v3 = gelu_f(v3);
            }
            if constexpr (EPI == EPI_WINREV || EPI == EPI_ADD) {
                uint2 rr = *(const uint2*)(res + orow * (long)N + cb);
                v0 += b2f((u16)(rr.x & 0xffff));
                v1 += b2f((u16)(rr.x >> 16));
                v2 += b2f((u16)(rr.y & 0xffff));
                v3 += b2f((u16)(rr.y >> 16));
            }
            if constexpr (SPLIT3) {
                u16* ob = (u16*)(n0 < 256 ? out0 : n0 < 512 ? out1 : out2);
                uint2 o;
                o.x = cvtpk(v0, v1);
                o.y = cvtpk(v2, v3);
                *(uint2*)(ob + orow * 256L + (cb & 255)) = o;
            } else if constexpr (OUTF32) {
                float4 o = {v0, v1, v2, v3};
                *(float4*)((float*)out0 + orow * (long)N + cb) = o;
            } else {
                uint2 o;
                o.x = cvtpk(v0, v1);
                o.y = cvtpk(v2, v3);
                *(uint2*)((u16*)out0 + orow * (long)N + cb) = o;
            }
        }
    }
}

// ---------------------------------------------------------------------------
// Window attention (window-ordered tokens): one wave per (window, head).
// Grid 4096 x 256 thr. Base-2 no-max softmax, sigma-permuted K columns,
// O^T-swapped PV, packed stores. LDS 51200B -> 3 blocks/CU, barrier-free.
// O written IN-PLACE over qb (disjoint column ownership).
// ---------------------------------------------------------------------------
__global__ __launch_bounds__(256, 3) void attn_kernel(
    const u16* __restrict__ qb, const u16* __restrict__ kb,
    const u16* __restrict__ vb, const float* __restrict__ biasp,
    u16* __restrict__ ob)
{
    __shared__ u16 lds[4 * 6400];
    const int wave = threadIdx.x >> 6, lane = threadIdx.x & 63;
    const int quad = lane >> 4, l16 = lane & 15;
    const int w = blockIdx.x >> 1;
    const int h = ((blockIdx.x & 1) << 2) + wave;
    u16* Pl = lds + wave * 6400;       // [2 ks][64 m][32 slots]
    u16* VT = Pl + 4096;               // [32 dims][72], slot-permuted V^T
    const long base = (long)w * 64 * 256 + h * 32;

    // ---- load Q fragments and sigma-permuted K fragments ----
    bf16x8 aq[4], bk4[4];
#pragma unroll
    for (int mi = 0; mi < 4; mi++)
        aq[mi] = *(const bf16x8*)(qb + base + (long)(mi * 16 + l16) * 256 + quad * 8);
#pragma unroll
    for (int ni = 0; ni < 4; ni++)
        bk4[ni] = *(const bf16x8*)(kb + base + (long)(4 * l16 + ni) * 256 + quad * 8);

    // ---- stage V^T with slot permutation (lane <-> token) ----
    {
        const int t = lane;
        const int s = ((t >> 4) & 1) * 32 + ((t >> 2) & 3) * 8 + (t >> 5) * 4 + (t & 3);
        const u16* vp = vb + base + (long)t * 256;
        union { uint4 v; u16 u[8]; } p0, p1, p2, p3;
        p0.v = *(const uint4*)(vp);
        p1.v = *(const uint4*)(vp + 8);
        p2.v = *(const uint4*)(vp + 16);
        p3.v = *(const uint4*)(vp + 24);
#pragma unroll
        for (int j = 0; j < 8; j++) {
            VT[j * 72 + s]        = p0.u[j];
            VT[(8 + j) * 72 + s]  = p1.u[j];
            VT[(16 + j) * 72 + s] = p2.u[j];
            VT[(24 + j) * 72 + s] = p3.u[j];
        }
    }

    // ---- S = Q @ K^T (columns sigma-permuted) ----
    f32x4 s[4][4];
#pragma unroll
    for (int i = 0; i < 4; i++)
#pragma unroll
        for (int j = 0; j < 4; j++) s[i][j] = (f32x4){0.f, 0.f, 0.f, 0.f};
    __builtin_amdgcn_s_setprio(1);
#pragma unroll
    for (int mi = 0; mi < 4; mi++)
#pragma unroll
        for (int ni = 0; ni < 4; ni++)
            s[mi][ni] = __builtin_amdgcn_mfma_f32_16x16x32_bf16(aq[mi], bk4[ni], s[mi][ni], 0, 0, 0);
    __builtin_amdgcn_s_setprio(0);

    // ---- softmax, base-2 domain, no max subtraction ----
    const float* bp = biasp + h * 4096;
    const float SC2 = 0.17677669529663687f * 1.4426950408889634f;  // scale*log2e
    const int pq = l16 & 3, pks = (l16 >> 2) & 1, ph = l16 >> 3;
#pragma unroll
    for (int mi = 0; mi < 4; mi++) {
        f32x4 bb[4];
#pragma unroll
        for (int ni = 0; ni < 4; ni++)
            bb[ni] = *(const f32x4*)(bp + ((mi * 4 + ni) << 8) + lane * 4);
#pragma unroll
        for (int r = 0; r < 4; r++) {
            float p[4];
#pragma unroll
            for (int ni = 0; ni < 4; ni++)
                p[ni] = __builtin_amdgcn_exp2f(s[mi][ni][r] * SC2 + bb[ni][r]);
            float sum = (p[0] + p[1]) + (p[2] + p[3]);
            for (int off = 1; off < 16; off <<= 1) sum += __shfl_xor(sum, off);
            float inv = __builtin_amdgcn_rcpf(sum);
            int mrow = mi * 16 + quad * 4 + r;
            uint2 w2;
            w2.x = cvtpk(p[0] * inv, p[1] * inv);
            w2.y = cvtpk(p[2] * inv, p[3] * inv);
            *(uint2*)&Pl[pks * 2048 + mrow * 32 + pq * 8 + ph * 4] = w2;
        }
    }

    // ---- O^T = V^T @ P^T  (M=32 dims, N=64 query rows, K=64 tokens) ----
    f32x4 o4[2][4];
#pragma unroll
    for (int i = 0; i < 2; i++)
#pragma unroll
        for (int j = 0; j < 4; j++) o4[i][j] = (f32x4){0.f, 0.f, 0.f, 0.f};
#pragma unroll
    for (int ks = 0; ks < 2; ks++) {
        bf16x8 at[2], pb[4];
#pragma unroll
        for (int mi = 0; mi < 2; mi++)
            at[mi] = *(const bf16x8*)&VT[(mi * 16 + l16) * 72 + ks * 32 + quad * 8];
#pragma unroll
        for (int nt = 0; nt < 4; nt++)
            pb[nt] = *(const bf16x8*)&Pl[ks * 2048 + (nt * 16 + l16) * 32 + quad * 8];
        __builtin_amdgcn_s_setprio(1);
#pragma unroll
        for (int mi = 0; mi < 2; mi++)
#pragma unroll
            for (int nt = 0; nt < 4; nt++)
                o4[mi][nt] = __builtin_amdgcn_mfma_f32_16x16x32_bf16(at[mi], pb[nt], o4[mi][nt], 0, 0, 0);
        __builtin_amdgcn_s_setprio(0);
    }

    // ---- store O (packed 4 dims/lane, in-place over this wave's q cols) ----
#pragma unroll
    for (int nt = 0; nt < 4; nt++)
#pragma unroll
        for (int mi = 0; mi < 2; mi++) {
            uint2 w2;
            w2.x = cvtpk(o4[mi][nt][0], o4[mi][nt][1]);
            w2.y = cvtpk(o4[mi][nt][2], o4[mi][nt][3]);
            *(uint2*)(ob + base + (long)(nt * 16 + l16) * 256 + mi * 16 + quad * 4) = w2;
        }
}

// ---------------------------------------------------------------------------
extern "C" void kernel_launch(void* const* d_in, const int* in_sizes, int n_in,
                              void* d_out, int out_size, void* d_ws, size_t ws_size,
                              hipStream_t stream)
{
    (void)in_sizes; (void)n_in; (void)out_size; (void)ws_size;
    const float* x    = (const float*)d_in[0];
    const float* feat = (const float*)d_in[1];
    const float* Wq = (const float*)d_in[2];   const float* bq = (const float*)d_in[3];
    const float* Wk = (const float*)d_in[4];   const float* bk = (const float*)d_in[5];
    const float* Wv = (const float*)d_in[6];   const float* bv = (const float*)d_in[7];
    const float* Wo = (const float*)d_in[8];   const float* bo = (const float*)d_in[9];
    const float* rpb = (const float*)d_in[10];
    const float* g1 = (const float*)d_in[11];  const float* be1 = (const float*)d_in[12];
    const float* g2 = (const float*)d_in[13];  const float* be2 = (const float*)d_in[14];
    const float* Wm1 = (const float*)d_in[15]; const float* bm1 = (const float*)d_in[16];
    const float* Wm2 = (const float*)d_in[17]; const float* bm2 = (const float*)d_in[18];
    const float* Wu1 = (const float*)d_in[19]; const float* bu1 = (const float*)d_in[20];
    const float* Wu2 = (const float*)d_in[21]; const float* bu2 = (const float*)d_in[22];
    const int* rel = (const int*)d_in[23];
    float* outp = (float*)d_out;

    char* ws = (char*)d_ws;
    u16* WqT  = (u16*)(ws);          // 768x256 contiguous (q,k,v) for merged GEMM
    u16* WkT  = WqT + 65536;
    u16* WvT  = WkT + 65536;
    u16* WoT  = WvT + 65536;
    u16* Wu1T = WoT + 65536;
    u16* Wu2T = Wu1T + 65536;
    u16* Wm1T = Wu2T + 65536;    // 1024 x 256
    u16* Wm2T = Wm1T + 262144;   // 256 x 1024
    float* biasf = (float*)(ws + 1835008);     // 128 KB rpb prepack
    float* bqkv  = (float*)(ws + 1966080);     // 768 f32 folded qkv bias
    float* bm1f  = (float*)(ws + 1970176);     // 1024 f32 folded mlp bias
    const long MB = 1024L * 1024;
    u16* S0 = (u16*)(ws + 2 * MB);      // q -> O -> mlp stats
    u16* S1 = (u16*)(ws + 66 * MB);     // k -> un -> hch
    u16* S2 = (u16*)(ws + 130 * MB);    // v -> u1h -> x2
    u16* xn  = (u16*)d_out;             // bf16 xn in first half of f32 d_out
    float* muP = (float*)((char*)d_out + 96 * MB);   // LN1 stats (dead early)
    float* rsP = (float*)((char*)d_out + 97 * MB);
    u16* qb  = S0;
    u16* kb  = S1;
    u16* vb  = S2;
    u16* O   = S0;     // attn output in-place over q
    u16* u1h = S2;     // unary hidden (v dead after attn)
    u16* un  = S1;     // unary output (k dead after attn)
    u16* x2  = S2;     // trunk (u1h dead after unary GEMM2)
    float* mu2 = (float*)S0;            // MLP LN stats (O dead after o-proj)
    float* rs2 = mu2 + MTOK;
    u16* hch = S1;     // mlp hidden chunk (un dead after o-proj)

    const dim3 blk(256);

    // weight transposes (+LN-gamma fold) + bias folds + rpb prepack
    transpose_f32_bf16<<<dim3(8, 8), blk, 0, stream>>>(Wq, g1, WqT, 256, 256);
    transpose_f32_bf16<<<dim3(8, 8), blk, 0, stream>>>(Wk, g1, WkT, 256, 256);
    transpose_f32_bf16<<<dim3(8, 8), blk, 0, stream>>>(Wv, g1, WvT, 256, 256);
    transpose_f32_bf16<<<dim3(8, 8), blk, 0, stream>>>(Wo, nullptr, WoT, 256, 256);
    transpose_f32_bf16<<<dim3(8, 8), blk, 0, stream>>>(Wu1, nullptr, Wu1T, 256, 256);
    transpose_f32_bf16<<<dim3(8, 8), blk, 0, stream>>>(Wu2, nullptr, Wu2T, 256, 256);
    transpose_f32_bf16<<<dim3(8, 32), blk, 0, stream>>>(Wm1, g2, Wm1T, 256, 1024);
    transpose_f32_bf16<<<dim3(32, 8), blk, 0, stream>>>(Wm2, nullptr, Wm2T, 1024, 256);
    bias_fold<<<dim3(1), blk, 0, stream>>>(Wq, bq, be1, bqkv, 256, 256);
    bias_fold<<<dim3(1), blk, 0, stream>>>(Wk, bk, be1, bqkv + 256, 256, 256);
    bias_fold<<<dim3(1), blk, 0, stream>>>(Wv, bv, be1, bqkv + 512, 256, 256);
    bias_fold<<<dim3(4), blk, 0, stream>>>(Wm1, bm1, be2, bm1f, 256, 1024);
    rpb_gather<<<dim3(128), blk, 0, stream>>>(rpb, rel, biasf);

    // LN1: stats + windowed transpose, feat -> xn
    ln_stats<<<dim3(512), blk, 0, stream>>>(feat, muP, rsP);
    ln_transpose<<<dim3(512), blk, 0, stream>>>(feat, muP, rsP, xn);

    // merged qkv projection (N=768, 3-way routed output)
    gemm_core<EPI_NONE, false, 0, true><<<dim3(6144), blk, 0, stream>>>(
        xn, WqT, bqkv, qb, kb, vb, nullptr, nullptr, nullptr, MTOK, 768, 256, 6);

    // window attention (O in-place over qb); k,v dead after
    attn_kernel<<<dim3(4096), blk, 0, stream>>>(qb, kb, vb, biasf, O);

    // unary path: gelu(x@Wu1+bu1) -> u1h (f32 A inline-cvt); @Wu2+bu2 -> un
    gemm_core<EPI_GELU, false, 1, false><<<dim3(2048), blk, 0, stream>>>(
        x, Wu1T, bu1, u1h, nullptr, nullptr, nullptr, nullptr, nullptr, MTOK, 256, 256, 2);
    gemm_core<EPI_NONE, false, 0, false><<<dim3(2048), blk, 0, stream>>>(
        u1h, Wu2T, bu2, un, nullptr, nullptr, nullptr, nullptr, nullptr, MTOK, 256, 256, 2);

    // o-proj + window reverse + add unary -> x2 (raw order)
    gemm_core<EPI_WINREV, false, 0, false><<<dim3(2048), blk, 0, stream>>>(
        O, WoT, bo, x2, nullptr, nullptr, un, nullptr, nullptr, MTOK, 256, 256, 2);

    // MLP: row stats once, then 4 chunks of 32768:
    //   out = x2 + gelu(((x2-mu)*rs)@Wm1'+bm1')@Wm2+bm2
    ln2_stats<<<dim3(32768), blk, 0, stream>>>(x2, mu2, rs2);
    for (int ch = 0; ch < 4; ch++) {
        const u16* x2c = x2 + (long)ch * 32768 * 256;
        float* outc = outp + (long)ch * 32768 * 256;
        gemm_core<EPI_GELU, false, 2, false><<<dim3(2048), blk, 0, stream>>>(
            x2c, Wm1T, bm1f, hch, nullptr, nullptr, nullptr,
            mu2 + (long)ch * 32768, rs2 + (long)ch * 32768, 32768, 1024, 256, 8);
        gemm_core<EPI_ADD, true, 0, false><<<dim3(512), blk, 0, stream>>>(
            hch, Wm2T, bm2, outc, nullptr, nullptr, x2c, nullptr, nullptr, 32768, 256, 1024, 2);
    }
}